// Round 13
// baseline (369.246 us; speedup 1.0000x reference)
//
#include <hip/hip_runtime.h>
#include <hip/hip_bf16.h>

#define LRELU(x) ((x) > 0.f ? (x) : 0.2f * (x))
#define CAP 96       // per-node bucket capacity; deg ~ Poisson(16)
#define BINBITS 7    // 128 nodes per fine bin
#define SBBITS 13    // 8192 nodes per superbin
#define NSB 7        // ceil(50000 / 8192)
#define SBCAP 136000 // per-superbin capacity; ~Poisson(131072), +15 sigma

typedef short bf16x8 __attribute__((ext_vector_type(8)));
typedef float f32x4 __attribute__((ext_vector_type(4)));

__device__ __forceinline__ float b2f(unsigned short u) {
  union { unsigned int i; float f; } v;
  v.i = ((unsigned int)u) << 16;
  return v.f;
}
__device__ __forceinline__ unsigned short f2b(float f) {
  unsigned int u = __float_as_uint(f);
  unsigned int r = (u + 0x7fffu + ((u >> 16) & 1u)) >> 16;
  return (unsigned short)r;
}

// ---------------------------------------------------------------------------
// prep_w1t: W1 [256,128] f32 -> W1^T [128,256] bf16 (for MFMA B fragments).
// ---------------------------------------------------------------------------
__global__ __launch_bounds__(256) void prep_w1t_kernel(
    const float* __restrict__ W, unsigned short* __restrict__ w1t) {
  int idx = blockIdx.x * 256 + threadIdx.x;  // over 128*256
  int n = idx >> 8, k = idx & 255;
  w1t[idx] = f2b(W[k * 128 + n]);
}

// ---------------------------------------------------------------------------
// gemm1_mfma: h1 = x @ W1 via mfma_f32_16x16x32_bf16, split-A for accuracy,
// with FUSED alpha epilogue. Block = 4 waves, 64 rows. (R11 version, proven)
// ---------------------------------------------------------------------------
__global__ __launch_bounds__(256) void gemm1_mfma_kernel(
    const float* __restrict__ x, const unsigned short* __restrict__ w1t,
    const float* __restrict__ atts, const float* __restrict__ attd,
    unsigned short* __restrict__ h1bf, float* __restrict__ asrc,
    float* __restrict__ adst, int N) {
  __shared__ unsigned short bsh[128 * 264];

  const int tid = threadIdx.x;
#pragma unroll
  for (int i = 0; i < 16; i++) {
    int idx = (i * 256 + tid) * 8;  // short index
    int row = idx >> 8;
    int k = idx & 255;
    *(uint4*)(bsh + row * 264 + k) = *(const uint4*)(w1t + row * 256 + k);
  }
  __syncthreads();

  const int m0 = blockIdx.x * 64 + (tid >> 6) * 16;
  if (m0 >= N) return;
  const int lane = tid & 63;
  const int row = lane & 15;
  const int quad = lane >> 4;

  f32x4 acc[8];
#pragma unroll
  for (int t = 0; t < 8; t++) acc[t] = (f32x4){0.f, 0.f, 0.f, 0.f};

  const float* ap = x + (size_t)(m0 + row) * 256 + quad * 8;
#pragma unroll
  for (int k0 = 0; k0 < 256; k0 += 32) {
    float4 av0 = *(const float4*)(ap + k0);
    float4 av1 = *(const float4*)(ap + k0 + 4);
    float af[8] = {av0.x, av0.y, av0.z, av0.w, av1.x, av1.y, av1.z, av1.w};
    bf16x8 ahi, alo;
#pragma unroll
    for (int j = 0; j < 8; j++) {
      unsigned short h = f2b(af[j]);
      ahi[j] = (short)h;
      alo[j] = (short)f2b(af[j] - b2f(h));
    }
#pragma unroll
    for (int t = 0; t < 8; t++) {
      bf16x8 b = *(const bf16x8*)(bsh + (t * 16 + row) * 264 + k0 + quad * 8);
      acc[t] = __builtin_amdgcn_mfma_f32_16x16x32_bf16(ahi, b, acc[t], 0, 0, 0);
      acc[t] = __builtin_amdgcn_mfma_f32_16x16x32_bf16(alo, b, acc[t], 0, 0, 0);
    }
  }
  // store h1 (bf16)
  unsigned short* op = h1bf + (size_t)(m0 + quad * 4) * 128 + row;
#pragma unroll
  for (int t = 0; t < 8; t++)
#pragma unroll
    for (int r = 0; r < 4; r++)
      op[(size_t)r * 128 + t * 16] = f2b(acc[t][r]);

  // fused alpha epilogue: per-head dots via 16-lane shuffle reduction.
  float asv[8], adv[8];
#pragma unroll
  for (int t = 0; t < 8; t++) {
    asv[t] = atts[t * 16 + row];
    adv[t] = attd[t * 16 + row];
  }
  float ps[4][4], pd[4][4];  // [head][r]
#pragma unroll
  for (int h = 0; h < 4; h++)
#pragma unroll
    for (int r = 0; r < 4; r++) {
      ps[h][r] = acc[2 * h][r] * asv[2 * h] + acc[2 * h + 1][r] * asv[2 * h + 1];
      pd[h][r] = acc[2 * h][r] * adv[2 * h] + acc[2 * h + 1][r] * adv[2 * h + 1];
    }
#pragma unroll
  for (int o = 1; o < 16; o <<= 1) {
#pragma unroll
    for (int h = 0; h < 4; h++)
#pragma unroll
      for (int r = 0; r < 4; r++) {
        ps[h][r] += __shfl_xor(ps[h][r], o);
        pd[h][r] += __shfl_xor(pd[h][r], o);
      }
  }
  if (row == 0) {
#pragma unroll
    for (int r = 0; r < 4; r++) {
      int m = m0 + quad * 4 + r;
#pragma unroll
      for (int h = 0; h < 4; h++) {
        asrc[m * 4 + h] = ps[h][r];
        adst[m * 4 + h] = pd[h][r];
      }
    }
  }
}

// ---------------------------------------------------------------------------
// superbin (phase A): partition edges into 7 superbins (dst>>13) with FULLY
// COALESCED writes. Per 256-edge batch: 8-entry LDS counting sort (cheap),
// one global atomic per (batch,superbin) to reserve a run, then thread i
// writes stage[i] to a lane-consecutive global position (~37-edge runs).
// ---------------------------------------------------------------------------
__global__ __launch_bounds__(256) void superbin_kernel(
    const int* __restrict__ ei, int E, int* __restrict__ gsb,
    unsigned int* __restrict__ sbin) {
  __shared__ int hist[NSB], base[NSB], binstart[NSB], cur[NSB];
  __shared__ unsigned int stage[256];
  __shared__ int gposs[256];
  const int tid = threadIdx.x;

  for (int e0 = blockIdx.x * 256; e0 < E; e0 += gridDim.x * 256) {
    const int e = e0 + tid;
    const bool valid = e < E;
    int s = 0, t = 0, sb = 0;
    if (valid) {
      s = ei[e];
      t = ei[(size_t)E + e];
      sb = t >> SBBITS;
    }
    if (tid < NSB) hist[tid] = 0;
    __syncthreads();
    if (valid) atomicAdd(&hist[sb], 1);
    __syncthreads();
    if (tid < NSB) {
      int c = hist[tid];
      base[tid] = c ? atomicAdd(&gsb[tid], c) : 0;
    }
    if (tid == 0) {
      int acc2 = 0;
      for (int i = 0; i < NSB; i++) {
        binstart[i] = acc2;
        cur[i] = acc2;
        acc2 += hist[i];
      }
    }
    __syncthreads();
    if (valid) {
      int loc = atomicAdd(&cur[sb], 1);
      stage[loc] = ((unsigned int)t << 16) | (unsigned int)s;
      int r = loc - binstart[sb];
      int gp = base[sb] + r;
      gposs[loc] = (gp < SBCAP) ? (sb * SBCAP + gp) : -1;
    }
    __syncthreads();
    const int ne = min(256, E - e0);
    if (tid < ne) {
      int gp = gposs[tid];
      if (gp >= 0) sbin[gp] = stage[tid];
    }
    __syncthreads();
  }
}

// ---------------------------------------------------------------------------
// sbin_to_buckets (phase B): one block per fine bin (128 dst nodes). Scan-
// filter the bin's superbin (L2-resident: all superbins total 3.8 MB),
// scatter matches into LDS buckets, flush coalesced. No global atomics.
// Fine bins never straddle superbins (8192 = 64 * 128).
// ---------------------------------------------------------------------------
__global__ __launch_bounds__(256) void sbin_to_buckets_kernel(
    const int* __restrict__ gsb, const unsigned int* __restrict__ sbin,
    int* __restrict__ cnt, unsigned short* __restrict__ buckets, int N) {
  __shared__ unsigned short lbkt[128 * CAP];  // 24 KB
  __shared__ int lcnt[128];
  const int b = blockIdx.x;
  const int tid = threadIdx.x;
  if (tid < 128) lcnt[tid] = 0;
  __syncthreads();
  const int sb = b >> (SBBITS - BINBITS);  // b/64
  const int ne = min(gsb[sb], SBCAP);
  const unsigned int* bp = sbin + (size_t)sb * SBCAP;
  const unsigned int want = (unsigned int)b;
  for (int i = tid; i < ne; i += 256) {
    unsigned int p = bp[i];
    if ((p >> (16 + BINBITS)) == want) {
      int ln = (p >> 16) & 127;
      int pos = atomicAdd(&lcnt[ln], 1);
      if (pos < CAP) lbkt[ln * CAP + pos] = (unsigned short)(p & 0xffff);
    }
  }
  __syncthreads();
  const int n0 = b << BINBITS;
  const int nn = min(128, N - n0);
  if (nn <= 0) return;
  if (tid < nn) cnt[n0 + tid] = lcnt[tid];
  const int total8 = (nn * CAP) >> 3;  // uint4 = 8 shorts
  uint4* d4 = (uint4*)(buckets + (size_t)n0 * CAP);
  const uint4* s4 = (const uint4*)lbkt;
  for (int i = tid; i < total8; i += 256) d4[i] = s4[i];
}

// ---------------------------------------------------------------------------
// agg1 (R11 version, proven 49.8 us): one WAVE per dst node; lane = 2
// channels; scalarized bucket indices (SALU address math).
// ---------------------------------------------------------------------------
__global__ __launch_bounds__(256) void agg1_kernel(
    const int* __restrict__ cnt, const unsigned short* __restrict__ buckets,
    const unsigned short* __restrict__ h1bf, const float* __restrict__ asrc,
    const float* __restrict__ adst, const float* __restrict__ b1,
    const float* __restrict__ gamma, const float* __restrict__ beta,
    const float* __restrict__ mean, const float* __restrict__ var,
    const float* __restrict__ W2, const float* __restrict__ as2,
    const float* __restrict__ ad2, float4* __restrict__ pk, int N) {
  const int wv = __builtin_amdgcn_readfirstlane(threadIdx.x >> 6);
  const int t = blockIdx.x * 4 + wv;
  if (t >= N) return;
  const int l = threadIdx.x & 63;
  const int h = l >> 4;
  const float ad = adst[t * 4 + h];

  float acc0 = 0.f, acc1 = 0.f, den = 0.f;
  const unsigned short* bkt = buckets + (size_t)t * CAP;
  const int deg = min(__builtin_amdgcn_readfirstlane(cnt[t]), CAP);
  int j = 0;
  for (; j + 4 <= deg; j += 4) {
    int s0 = __builtin_amdgcn_readfirstlane((int)bkt[j]);
    int s1 = __builtin_amdgcn_readfirstlane((int)bkt[j + 1]);
    int s2 = __builtin_amdgcn_readfirstlane((int)bkt[j + 2]);
    int s3 = __builtin_amdgcn_readfirstlane((int)bkt[j + 3]);
    unsigned int p0 = *(const unsigned int*)(h1bf + (size_t)s0 * 128 + 2 * l);
    unsigned int p1 = *(const unsigned int*)(h1bf + (size_t)s1 * 128 + 2 * l);
    unsigned int p2 = *(const unsigned int*)(h1bf + (size_t)s2 * 128 + 2 * l);
    unsigned int p3 = *(const unsigned int*)(h1bf + (size_t)s3 * 128 + 2 * l);
    float w0 = __expf(LRELU(asrc[s0 * 4 + h] + ad));
    float w1 = __expf(LRELU(asrc[s1 * 4 + h] + ad));
    float w2 = __expf(LRELU(asrc[s2 * 4 + h] + ad));
    float w3 = __expf(LRELU(asrc[s3 * 4 + h] + ad));
    acc0 += w0 * b2f((unsigned short)(p0 & 0xffff)) +
            w1 * b2f((unsigned short)(p1 & 0xffff)) +
            w2 * b2f((unsigned short)(p2 & 0xffff)) +
            w3 * b2f((unsigned short)(p3 & 0xffff));
    acc1 += w0 * b2f((unsigned short)(p0 >> 16)) +
            w1 * b2f((unsigned short)(p1 >> 16)) +
            w2 * b2f((unsigned short)(p2 >> 16)) +
            w3 * b2f((unsigned short)(p3 >> 16));
    den += w0 + w1 + w2 + w3;
  }
  for (; j < deg; j++) {
    int s0 = __builtin_amdgcn_readfirstlane((int)bkt[j]);
    unsigned int p0 = *(const unsigned int*)(h1bf + (size_t)s0 * 128 + 2 * l);
    float w0 = __expf(LRELU(asrc[s0 * 4 + h] + ad));
    acc0 += w0 * b2f((unsigned short)(p0 & 0xffff));
    acc1 += w0 * b2f((unsigned short)(p0 >> 16));
    den += w0;
  }
  {  // self-loop
    unsigned int p0 = *(const unsigned int*)(h1bf + (size_t)t * 128 + 2 * l);
    float w0 = __expf(LRELU(asrc[t * 4 + h] + ad));
    acc0 += w0 * b2f((unsigned short)(p0 & 0xffff));
    acc1 += w0 * b2f((unsigned short)(p0 >> 16));
    den += w0;
  }
  const int c0 = 2 * l;
  float inv = 1.f / den;
  float v0 = acc0 * inv + b1[c0];
  float v1 = acc1 * inv + b1[c0 + 1];
  v0 = (v0 - mean[c0]) * rsqrtf(var[c0] + 1e-5f) * gamma[c0] + beta[c0];
  v1 = (v1 - mean[c0 + 1]) * rsqrtf(var[c0 + 1] + 1e-5f) * gamma[c0 + 1] +
       beta[c0 + 1];
  v0 = v0 > 0.f ? v0 : 0.f;
  v1 = v1 > 0.f ? v1 : 0.f;

  // fused layer-2 node transform: g = h2 @ W2 (wave reduction), pack pk
  float g0 = v0 * W2[c0 * 2 + 0] + v1 * W2[(c0 + 1) * 2 + 0];
  float g1 = v0 * W2[c0 * 2 + 1] + v1 * W2[(c0 + 1) * 2 + 1];
#pragma unroll
  for (int o = 32; o > 0; o >>= 1) {
    g0 += __shfl_down(g0, o);
    g1 += __shfl_down(g1, o);
  }
  if (l == 0) {
    float4 p;
    p.x = g0;
    p.y = g1;
    p.z = g0 * as2[0] + g1 * as2[1];
    p.w = g0 * ad2[0] + g1 * ad2[1];
    pk[t] = p;
  }
}

// ---------------------------------------------------------------------------
// agg2: layer-2 gather-aggregate -> d_out. 16-lane group per node. (unchanged)
// ---------------------------------------------------------------------------
__global__ __launch_bounds__(256) void agg2_kernel(
    const int* __restrict__ cnt, const unsigned short* __restrict__ buckets,
    const float4* __restrict__ pk, const float* __restrict__ b2,
    float* __restrict__ out, int N) {
  const int t = blockIdx.x * 16 + (threadIdx.x >> 4);
  if (t >= N) return;
  const int lg = threadIdx.x & 15;
  float4 pt = pk[t];
  const float ad = pt.w;
  float a0 = 0.f, a1 = 0.f, den = 0.f;
  const unsigned short* bkt = buckets + (size_t)t * CAP;
  const int deg = min(cnt[t], CAP);
  for (int j = lg; j < deg; j += 16) {
    float4 p = pk[bkt[j]];
    float w = __expf(LRELU(p.z + ad));
    a0 += w * p.x;
    a1 += w * p.y;
    den += w;
  }
#pragma unroll
  for (int o = 8; o > 0; o >>= 1) {
    a0 += __shfl_xor(a0, o);
    a1 += __shfl_xor(a1, o);
    den += __shfl_xor(den, o);
  }
  if (lg == 0) {
    float w = __expf(LRELU(pt.z + ad));  // self-loop
    a0 += w * pt.x;
    a1 += w * pt.y;
    den += w;
    float2 o2;
    o2.x = a0 / den + b2[0];
    o2.y = a1 / den + b2[1];
    *(float2*)(out + (size_t)t * 2) = o2;
  }
}

extern "C" void kernel_launch(void* const* d_in, const int* in_sizes, int n_in,
                              void* d_out, int out_size, void* d_ws,
                              size_t ws_size, hipStream_t stream) {
  const float* x      = (const float*)d_in[0];
  const int*   ei     = (const int*)d_in[1];
  const float* W1     = (const float*)d_in[2];
  const float* atts1  = (const float*)d_in[3];
  const float* attd1  = (const float*)d_in[4];
  const float* b1     = (const float*)d_in[5];
  const float* gamma  = (const float*)d_in[6];
  const float* beta   = (const float*)d_in[7];
  const float* mean   = (const float*)d_in[8];
  const float* var    = (const float*)d_in[9];
  const float* W2     = (const float*)d_in[10];
  const float* atts2  = (const float*)d_in[11];
  const float* attd2  = (const float*)d_in[12];
  const float* b2     = (const float*)d_in[13];
  float* out = (float*)d_out;

  const int N = in_sizes[0] / 256;   // 50000
  const int E = in_sizes[1] / 2;     // 800000
  const int nbins = (N + (1 << BINBITS) - 1) >> BINBITS;  // 391

  // workspace layout
  char* ws = (char*)d_ws;
  size_t off = 0;
  unsigned short* h1bf = (unsigned short*)(ws + off); off += (size_t)N * 128 * 2;
  float* asrc1 = (float*)(ws + off); off += (size_t)N * 4 * 4;
  float* adst1 = (float*)(ws + off); off += (size_t)N * 4 * 4;
  float4* pk   = (float4*)(ws + off); off += (size_t)N * 16;
  int*   cnt   = (int*)  (ws + off); off += (size_t)N * 4;
  int*   gsb   = (int*)  (ws + off); off += 64 * 4;
  unsigned short* w1t = (unsigned short*)(ws + off); off += 128 * 256 * 2;
  unsigned short* buckets = (unsigned short*)(ws + off);
  off += (size_t)N * CAP * 2;
  unsigned int* sbin = (unsigned int*)(ws + off);
  off += (size_t)NSB * SBCAP * 4;

  // --- bucket build: tiny memset + coalesced superbin pass + scan-filter ---
  hipMemsetAsync(gsb, 0, 64 * 4, stream);
  superbin_kernel<<<512, 256, 0, stream>>>(ei, E, gsb, sbin);
  sbin_to_buckets_kernel<<<nbins, 256, 0, stream>>>(gsb, sbin, cnt, buckets, N);

  // --- layer 1 (gemm with fused alpha epilogue) ---
  prep_w1t_kernel<<<128, 256, 0, stream>>>(W1, w1t);
  gemm1_mfma_kernel<<<(N + 63) / 64, 256, 0, stream>>>(
      x, w1t, atts1, attd1, h1bf, asrc1, adst1, N);
  agg1_kernel<<<(N + 3) / 4, 256, 0, stream>>>(cnt, buckets, h1bf, asrc1,
                                               adst1, b1, gamma, beta, mean,
                                               var, W2, atts2, attd2, pk, N);

  // --- layer 2 ---
  agg2_kernel<<<(N + 15) / 16, 256, 0, stream>>>(cnt, buckets, pk, b2, out, N);
}

// Round 14
// 212.768 us; speedup vs baseline: 1.7354x; 1.7354x over previous
//
#include <hip/hip_runtime.h>
#include <hip/hip_bf16.h>

#define LRELU(x) ((x) > 0.f ? (x) : 0.2f * (x))
#define CAP 96       // per-node bucket capacity; deg ~ Poisson(16)
#define BINBITS 7    // 128 nodes per bin
#define BINCAP 2600  // per-bin edge capacity; ~Poisson(2048), +12 sigma

typedef short bf16x8 __attribute__((ext_vector_type(8)));
typedef float f32x4 __attribute__((ext_vector_type(4)));

__device__ __forceinline__ float b2f(unsigned short u) {
  union { unsigned int i; float f; } v;
  v.i = ((unsigned int)u) << 16;
  return v.f;
}
__device__ __forceinline__ unsigned short f2b(float f) {
  unsigned int u = __float_as_uint(f);
  unsigned int r = (u + 0x7fffu + ((u >> 16) & 1u)) >> 16;
  return (unsigned short)r;
}

// ---------------------------------------------------------------------------
// prep_w1t: W1 [256,128] f32 -> W1^T [128,256] bf16; block 0 also zeroes
// gcnt (replaces the hipMemsetAsync dispatch; runs before bin_edges).
// ---------------------------------------------------------------------------
__global__ __launch_bounds__(256) void prep_w1t_kernel(
    const float* __restrict__ W, unsigned short* __restrict__ w1t,
    int* __restrict__ gcnt) {
  if (blockIdx.x == 0) {
    gcnt[threadIdx.x] = 0;
    gcnt[256 + threadIdx.x] = 0;
  }
  int idx = blockIdx.x * 256 + threadIdx.x;  // over 128*256
  int n = idx >> 8, k = idx & 255;
  w1t[idx] = f2b(W[k * 128 + n]);
}

// ---------------------------------------------------------------------------
// gemm1_mfma: h1 = x @ W1 via mfma_f32_16x16x32_bf16, split-A for accuracy,
// with FUSED alpha epilogue. Block = 4 waves, 64 rows. (R11 version, proven)
// ---------------------------------------------------------------------------
__global__ __launch_bounds__(256) void gemm1_mfma_kernel(
    const float* __restrict__ x, const unsigned short* __restrict__ w1t,
    const float* __restrict__ atts, const float* __restrict__ attd,
    unsigned short* __restrict__ h1bf, float* __restrict__ asrc,
    float* __restrict__ adst, int N) {
  __shared__ unsigned short bsh[128 * 264];

  const int tid = threadIdx.x;
#pragma unroll
  for (int i = 0; i < 16; i++) {
    int idx = (i * 256 + tid) * 8;  // short index
    int row = idx >> 8;
    int k = idx & 255;
    *(uint4*)(bsh + row * 264 + k) = *(const uint4*)(w1t + row * 256 + k);
  }
  __syncthreads();

  const int m0 = blockIdx.x * 64 + (tid >> 6) * 16;
  if (m0 >= N) return;
  const int lane = tid & 63;
  const int row = lane & 15;
  const int quad = lane >> 4;

  f32x4 acc[8];
#pragma unroll
  for (int t = 0; t < 8; t++) acc[t] = (f32x4){0.f, 0.f, 0.f, 0.f};

  const float* ap = x + (size_t)(m0 + row) * 256 + quad * 8;
#pragma unroll
  for (int k0 = 0; k0 < 256; k0 += 32) {
    float4 av0 = *(const float4*)(ap + k0);
    float4 av1 = *(const float4*)(ap + k0 + 4);
    float af[8] = {av0.x, av0.y, av0.z, av0.w, av1.x, av1.y, av1.z, av1.w};
    bf16x8 ahi, alo;
#pragma unroll
    for (int j = 0; j < 8; j++) {
      unsigned short h = f2b(af[j]);
      ahi[j] = (short)h;
      alo[j] = (short)f2b(af[j] - b2f(h));
    }
#pragma unroll
    for (int t = 0; t < 8; t++) {
      bf16x8 b = *(const bf16x8*)(bsh + (t * 16 + row) * 264 + k0 + quad * 8);
      acc[t] = __builtin_amdgcn_mfma_f32_16x16x32_bf16(ahi, b, acc[t], 0, 0, 0);
      acc[t] = __builtin_amdgcn_mfma_f32_16x16x32_bf16(alo, b, acc[t], 0, 0, 0);
    }
  }
  // store h1 (bf16)
  unsigned short* op = h1bf + (size_t)(m0 + quad * 4) * 128 + row;
#pragma unroll
  for (int t = 0; t < 8; t++)
#pragma unroll
    for (int r = 0; r < 4; r++)
      op[(size_t)r * 128 + t * 16] = f2b(acc[t][r]);

  // fused alpha epilogue: per-head dots via 16-lane shuffle reduction.
  float asv[8], adv[8];
#pragma unroll
  for (int t = 0; t < 8; t++) {
    asv[t] = atts[t * 16 + row];
    adv[t] = attd[t * 16 + row];
  }
  float ps[4][4], pd[4][4];  // [head][r]
#pragma unroll
  for (int h = 0; h < 4; h++)
#pragma unroll
    for (int r = 0; r < 4; r++) {
      ps[h][r] = acc[2 * h][r] * asv[2 * h] + acc[2 * h + 1][r] * asv[2 * h + 1];
      pd[h][r] = acc[2 * h][r] * adv[2 * h] + acc[2 * h + 1][r] * adv[2 * h + 1];
    }
#pragma unroll
  for (int o = 1; o < 16; o <<= 1) {
#pragma unroll
    for (int h = 0; h < 4; h++)
#pragma unroll
      for (int r = 0; r < 4; r++) {
        ps[h][r] += __shfl_xor(ps[h][r], o);
        pd[h][r] += __shfl_xor(pd[h][r], o);
      }
  }
  if (row == 0) {
#pragma unroll
    for (int r = 0; r < 4; r++) {
      int m = m0 + quad * 4 + r;
#pragma unroll
      for (int h = 0; h < 4; h++) {
        asrc[m * 4 + h] = ps[h][r];
        adst[m * 4 + h] = pd[h][r];
      }
    }
  }
}

// ---------------------------------------------------------------------------
// bin_edges (phase A): coarse-bin edges by dst>>BINBITS into fixed bins.
// (R11 version, proven)
// ---------------------------------------------------------------------------
__global__ __launch_bounds__(256) void bin_edges_kernel(
    const int* __restrict__ ei, int E, int* __restrict__ gcnt,
    unsigned int* __restrict__ binned, int nbins) {
  __shared__ int hist[512];
  __shared__ int base[512];
  const int tid = threadIdx.x;
  for (int i = tid; i < 512; i += 256) hist[i] = 0;
  __syncthreads();
  const int chunk = (E + gridDim.x - 1) / gridDim.x;
  const int e0 = blockIdx.x * chunk;
  const int e1 = min(e0 + chunk, E);
  for (int e = e0 + tid; e < e1; e += 256)
    atomicAdd(&hist[ei[(size_t)E + e] >> BINBITS], 1);
  __syncthreads();
  for (int i = tid; i < nbins; i += 256)
    if (hist[i] > 0) base[i] = atomicAdd(&gcnt[i], hist[i]);
  __syncthreads();
  for (int i = tid; i < 512; i += 256) hist[i] = 0;
  __syncthreads();
  for (int e = e0 + tid; e < e1; e += 256) {
    int s = ei[e];
    int t = ei[(size_t)E + e];
    int b = t >> BINBITS;
    int pos = base[b] + atomicAdd(&hist[b], 1);
    if (pos < BINCAP)
      binned[(size_t)b * BINCAP + pos] = ((unsigned int)t << 16) | (unsigned int)s;
  }
}

// ---------------------------------------------------------------------------
// bin_to_buckets (phase B): one block per bin (128 dst nodes). (R11 version)
// ---------------------------------------------------------------------------
__global__ __launch_bounds__(256) void bin_to_buckets_kernel(
    const int* __restrict__ gcnt, const unsigned int* __restrict__ binned,
    int* __restrict__ cnt, unsigned short* __restrict__ buckets, int N) {
  __shared__ unsigned short lbkt[128 * CAP];  // 24 KB
  __shared__ int lcnt[128];
  const int b = blockIdx.x;
  const int tid = threadIdx.x;
  if (tid < 128) lcnt[tid] = 0;
  __syncthreads();
  const int ne = min(gcnt[b], BINCAP);
  const unsigned int* bp = binned + (size_t)b * BINCAP;
  for (int i = tid; i < ne; i += 256) {
    unsigned int p = bp[i];
    int ln = (p >> 16) & 127;
    int pos = atomicAdd(&lcnt[ln], 1);
    if (pos < CAP) lbkt[ln * CAP + pos] = (unsigned short)(p & 0xffff);
  }
  __syncthreads();
  const int n0 = b << BINBITS;
  const int nn = min(128, N - n0);
  if (nn <= 0) return;
  if (tid < nn) cnt[n0 + tid] = lcnt[tid];
  const int total8 = (nn * CAP) >> 3;  // uint4 = 8 shorts
  uint4* d4 = (uint4*)(buckets + (size_t)n0 * CAP);
  const uint4* s4 = (const uint4*)lbkt;
  for (int i = tid; i < total8; i += 256) d4[i] = s4[i];
}

// ---------------------------------------------------------------------------
// agg1 (R11 version, proven 49.8 us) with node-range [n0base, nend) so the
// iteration can be split into two dispatches (top-5 visibility probe).
// ---------------------------------------------------------------------------
__global__ __launch_bounds__(256) void agg1_kernel(
    const int* __restrict__ cnt, const unsigned short* __restrict__ buckets,
    const unsigned short* __restrict__ h1bf, const float* __restrict__ asrc,
    const float* __restrict__ adst, const float* __restrict__ b1,
    const float* __restrict__ gamma, const float* __restrict__ beta,
    const float* __restrict__ mean, const float* __restrict__ var,
    const float* __restrict__ W2, const float* __restrict__ as2,
    const float* __restrict__ ad2, float4* __restrict__ pk, int n0base,
    int nend) {
  const int wv = __builtin_amdgcn_readfirstlane(threadIdx.x >> 6);
  const int t = n0base + blockIdx.x * 4 + wv;
  if (t >= nend) return;
  const int l = threadIdx.x & 63;
  const int h = l >> 4;
  const float ad = adst[t * 4 + h];

  float acc0 = 0.f, acc1 = 0.f, den = 0.f;
  const unsigned short* bkt = buckets + (size_t)t * CAP;
  const int deg = min(__builtin_amdgcn_readfirstlane(cnt[t]), CAP);
  int j = 0;
  for (; j + 4 <= deg; j += 4) {
    int s0 = __builtin_amdgcn_readfirstlane((int)bkt[j]);
    int s1 = __builtin_amdgcn_readfirstlane((int)bkt[j + 1]);
    int s2 = __builtin_amdgcn_readfirstlane((int)bkt[j + 2]);
    int s3 = __builtin_amdgcn_readfirstlane((int)bkt[j + 3]);
    unsigned int p0 = *(const unsigned int*)(h1bf + (size_t)s0 * 128 + 2 * l);
    unsigned int p1 = *(const unsigned int*)(h1bf + (size_t)s1 * 128 + 2 * l);
    unsigned int p2 = *(const unsigned int*)(h1bf + (size_t)s2 * 128 + 2 * l);
    unsigned int p3 = *(const unsigned int*)(h1bf + (size_t)s3 * 128 + 2 * l);
    float w0 = __expf(LRELU(asrc[s0 * 4 + h] + ad));
    float w1 = __expf(LRELU(asrc[s1 * 4 + h] + ad));
    float w2 = __expf(LRELU(asrc[s2 * 4 + h] + ad));
    float w3 = __expf(LRELU(asrc[s3 * 4 + h] + ad));
    acc0 += w0 * b2f((unsigned short)(p0 & 0xffff)) +
            w1 * b2f((unsigned short)(p1 & 0xffff)) +
            w2 * b2f((unsigned short)(p2 & 0xffff)) +
            w3 * b2f((unsigned short)(p3 & 0xffff));
    acc1 += w0 * b2f((unsigned short)(p0 >> 16)) +
            w1 * b2f((unsigned short)(p1 >> 16)) +
            w2 * b2f((unsigned short)(p2 >> 16)) +
            w3 * b2f((unsigned short)(p3 >> 16));
    den += w0 + w1 + w2 + w3;
  }
  for (; j < deg; j++) {
    int s0 = __builtin_amdgcn_readfirstlane((int)bkt[j]);
    unsigned int p0 = *(const unsigned int*)(h1bf + (size_t)s0 * 128 + 2 * l);
    float w0 = __expf(LRELU(asrc[s0 * 4 + h] + ad));
    acc0 += w0 * b2f((unsigned short)(p0 & 0xffff));
    acc1 += w0 * b2f((unsigned short)(p0 >> 16));
    den += w0;
  }
  {  // self-loop
    unsigned int p0 = *(const unsigned int*)(h1bf + (size_t)t * 128 + 2 * l);
    float w0 = __expf(LRELU(asrc[t * 4 + h] + ad));
    acc0 += w0 * b2f((unsigned short)(p0 & 0xffff));
    acc1 += w0 * b2f((unsigned short)(p0 >> 16));
    den += w0;
  }
  const int c0 = 2 * l;
  float inv = 1.f / den;
  float v0 = acc0 * inv + b1[c0];
  float v1 = acc1 * inv + b1[c0 + 1];
  v0 = (v0 - mean[c0]) * rsqrtf(var[c0] + 1e-5f) * gamma[c0] + beta[c0];
  v1 = (v1 - mean[c0 + 1]) * rsqrtf(var[c0 + 1] + 1e-5f) * gamma[c0 + 1] +
       beta[c0 + 1];
  v0 = v0 > 0.f ? v0 : 0.f;
  v1 = v1 > 0.f ? v1 : 0.f;

  // fused layer-2 node transform: g = h2 @ W2 (wave reduction), pack pk
  float g0 = v0 * W2[c0 * 2 + 0] + v1 * W2[(c0 + 1) * 2 + 0];
  float g1 = v0 * W2[c0 * 2 + 1] + v1 * W2[(c0 + 1) * 2 + 1];
#pragma unroll
  for (int o = 32; o > 0; o >>= 1) {
    g0 += __shfl_down(g0, o);
    g1 += __shfl_down(g1, o);
  }
  if (l == 0) {
    float4 p;
    p.x = g0;
    p.y = g1;
    p.z = g0 * as2[0] + g1 * as2[1];
    p.w = g0 * ad2[0] + g1 * ad2[1];
    pk[t] = p;
  }
}

// ---------------------------------------------------------------------------
// agg2: layer-2 gather-aggregate -> d_out. 16-lane group per node. (unchanged)
// ---------------------------------------------------------------------------
__global__ __launch_bounds__(256) void agg2_kernel(
    const int* __restrict__ cnt, const unsigned short* __restrict__ buckets,
    const float4* __restrict__ pk, const float* __restrict__ b2,
    float* __restrict__ out, int N) {
  const int t = blockIdx.x * 16 + (threadIdx.x >> 4);
  if (t >= N) return;
  const int lg = threadIdx.x & 15;
  float4 pt = pk[t];
  const float ad = pt.w;
  float a0 = 0.f, a1 = 0.f, den = 0.f;
  const unsigned short* bkt = buckets + (size_t)t * CAP;
  const int deg = min(cnt[t], CAP);
  for (int j = lg; j < deg; j += 16) {
    float4 p = pk[bkt[j]];
    float w = __expf(LRELU(p.z + ad));
    a0 += w * p.x;
    a1 += w * p.y;
    den += w;
  }
#pragma unroll
  for (int o = 8; o > 0; o >>= 1) {
    a0 += __shfl_xor(a0, o);
    a1 += __shfl_xor(a1, o);
    den += __shfl_xor(den, o);
  }
  if (lg == 0) {
    float w = __expf(LRELU(pt.z + ad));  // self-loop
    a0 += w * pt.x;
    a1 += w * pt.y;
    den += w;
    float2 o2;
    o2.x = a0 / den + b2[0];
    o2.y = a1 / den + b2[1];
    *(float2*)(out + (size_t)t * 2) = o2;
  }
}

extern "C" void kernel_launch(void* const* d_in, const int* in_sizes, int n_in,
                              void* d_out, int out_size, void* d_ws,
                              size_t ws_size, hipStream_t stream) {
  const float* x      = (const float*)d_in[0];
  const int*   ei     = (const int*)d_in[1];
  const float* W1     = (const float*)d_in[2];
  const float* atts1  = (const float*)d_in[3];
  const float* attd1  = (const float*)d_in[4];
  const float* b1     = (const float*)d_in[5];
  const float* gamma  = (const float*)d_in[6];
  const float* beta   = (const float*)d_in[7];
  const float* mean   = (const float*)d_in[8];
  const float* var    = (const float*)d_in[9];
  const float* W2     = (const float*)d_in[10];
  const float* atts2  = (const float*)d_in[11];
  const float* attd2  = (const float*)d_in[12];
  const float* b2     = (const float*)d_in[13];
  float* out = (float*)d_out;

  const int N = in_sizes[0] / 256;   // 50000
  const int E = in_sizes[1] / 2;     // 800000
  const int nbins = (N + (1 << BINBITS) - 1) >> BINBITS;  // 391

  // workspace layout
  char* ws = (char*)d_ws;
  size_t off = 0;
  unsigned short* h1bf = (unsigned short*)(ws + off); off += (size_t)N * 128 * 2;
  float* asrc1 = (float*)(ws + off); off += (size_t)N * 4 * 4;
  float* adst1 = (float*)(ws + off); off += (size_t)N * 4 * 4;
  float4* pk   = (float4*)(ws + off); off += (size_t)N * 16;
  int*   cnt   = (int*)  (ws + off); off += (size_t)N * 4;
  int*   gcnt  = (int*)  (ws + off); off += 512 * 4;
  unsigned short* w1t = (unsigned short*)(ws + off); off += 128 * 256 * 2;
  unsigned short* buckets = (unsigned short*)(ws + off);
  off += (size_t)N * CAP * 2;
  unsigned int* binned = (unsigned int*)(ws + off);
  off += (size_t)nbins * BINCAP * 4;

  // --- prep (also zeroes gcnt, replacing the memset dispatch) ---
  prep_w1t_kernel<<<128, 256, 0, stream>>>(W1, w1t, gcnt);

  // --- bucket build: 2-phase hierarchical scatter (R11, proven) ---
  bin_edges_kernel<<<512, 256, 0, stream>>>(ei, E, gcnt, binned, nbins);
  bin_to_buckets_kernel<<<nbins, 256, 0, stream>>>(gcnt, binned, cnt, buckets,
                                                   N);

  // --- layer 1 (gemm with fused alpha epilogue) ---
  gemm1_mfma_kernel<<<(N + 63) / 64, 256, 0, stream>>>(
      x, w1t, atts1, attd1, h1bf, asrc1, adst1, N);
  // agg1 split into two half-range dispatches (measurement probe: lets the
  // true #2 kernel surface in rocprof's top-5)
  const int half = (N / 2 + 3) & ~3;
  agg1_kernel<<<(half + 3) / 4, 256, 0, stream>>>(
      cnt, buckets, h1bf, asrc1, adst1, b1, gamma, beta, mean, var, W2, atts2,
      attd2, pk, 0, half);
  agg1_kernel<<<(N - half + 3) / 4, 256, 0, stream>>>(
      cnt, buckets, h1bf, asrc1, adst1, b1, gamma, beta, mean, var, W2, atts2,
      attd2, pk, half, N);

  // --- layer 2 ---
  agg2_kernel<<<(N + 15) / 16, 256, 0, stream>>>(cnt, buckets, pk, b2, out, N);
}